// Round 1
// baseline (5252.008 us; speedup 1.0000x reference)
//
#include <hip/hip_runtime.h>
#include <math.h>

// 2-layer LSTM, B=64, T=512, F=256, H=512, fp32 — persistent cooperative kernel.
// R6: halve the coherent-L3 broadcast. R5 (8243us) moved weights to VGPRs; step
// time ~16us matches 48 MB/step of agent-coherent h reads at ~3 TB/s => the
// kernel is L3-coherent-BW bound, not latency or MFMA bound. Traffic = h size x
// blocks-per-layer, so: 64 blocks/layer x 8 units/block (was 128 x 4). Weight
// registers would double to 256 VGPRs, so only W-hi stays in VGPRs (128 regs);
// W-lo bf16 fragments move to LDS (64 KB, conflict-free ds_read_b128, ~1us/step
// issue, hidden under L3 stalls). Each wave keeps its K-half (h still read once
// per block) and computes TWO N-tiles sharing every A-fragment load.
// Slot barrier: 128 participants (was 256); poll via 8B pair-loads, 64/iter
// (was 256 x 4B) — ~8x less poll traffic.
// Precision scheme unchanged: h and W split hi+lo bf16, 3 MFMAs per K=32 chunk
// per N-tile (hi*hi, hi*lo, lo*hi), fp32 accumulate. c-state in registers
// (thread (b,ul) owns c[b][u]). h0 ring depth 4 (layer0 two steps of WAR slack),
// h1 ring depth 2.
//
// Partition: blocks[0,64)=layer0, [64,128)=layer1; block = 8 hidden units
// (32 gate rows = 2 MFMA N-tiles); 512 threads = 8 waves: wave = (mt m-tile of
// 16 batches, kh K-half). MFMA 16x16x32 bf16: A=h rows (lane&15=batch,
// quad*8+j=k), B=W (lane&15=gate col), C: row=quad*4+reg=batch, col=lane&15.

#define TT 512
#define FF 256
#define HH 512
#define NB 128

typedef __attribute__((ext_vector_type(4)))  float f32x4;
typedef __attribute__((ext_vector_type(8)))  short short8;
typedef __attribute__((ext_vector_type(16))) short short16;

__device__ __forceinline__ float sigmoidf_(float v){ return 1.0f/(1.0f+__expf(-v)); }

__device__ __forceinline__ unsigned short f2bf(float f){          // RTNE fp32->bf16
    unsigned u = __float_as_uint(f);
    u += 0x7FFFu + ((u>>16)&1u);
    return (unsigned short)(u>>16);
}
__device__ __forceinline__ float bf2f(unsigned short h){ return __uint_as_float(((unsigned)h)<<16); }

__device__ __forceinline__ unsigned long long ld8coh(const unsigned* p){
    return __hip_atomic_load((const unsigned long long*)p, __ATOMIC_RELAXED, __HIP_MEMORY_SCOPE_AGENT);
}
__device__ __forceinline__ void st4coh(unsigned* p, unsigned v){
    __hip_atomic_store(p, v, __ATOMIC_RELAXED, __HIP_MEMORY_SCOPE_AGENT);
}
__device__ __forceinline__ void stslot(int* p, int v){
    __hip_atomic_store(p, v, __ATOMIC_RELAXED, __HIP_MEMORY_SCOPE_AGENT);
}

union HU { unsigned long long q[4]; short16 v; };

__device__ __forceinline__ void split8(const float* v, short8& h8, short8& l8){
#pragma unroll
    for (int j=0;j<8;++j){
        const unsigned short hh = f2bf(v[j]);
        h8[j] = (short)hh;
        l8[j] = (short)f2bf(v[j]-bf2f(hh));
    }
}

#define MFMA(a,b,c) __builtin_amdgcn_mfma_f32_16x16x32_bf16((a),(b),(c),0,0,0)

struct SMem {
    short8 wlo[2*16*2*64];        // [kh][c:16][nt:2][quad*16+nn] — 64 KB (layer0 uses 12 c's)
    float  part[2][4][16][33];    // [kh][mt][row=batch-in-tile][col=nt*16+nn] — 16.5 KB
};

template<int LAYER>
__device__ __forceinline__ void run(
    const float* __restrict__ x,
    const float* __restrict__ WA, const float* __restrict__ WB,
    const float* __restrict__ bi, const float* __restrict__ bh,
    unsigned* __restrict__ hp0, unsigned* __restrict__ hp1,
    float* __restrict__ out, int* __restrict__ slots,
    const int tile, SMem* sm)
{
    const int tid  = threadIdx.x;
    const int lane = tid & 63;
    const int wv   = __builtin_amdgcn_readfirstlane(tid>>6);
    const int mt   = wv & 3;              // m-tile: batches [16*mt, 16*mt+16)
    const int kh   = wv >> 2;             // K-half
    const int nn   = lane & 15;           // gate col / A batch row within tile
    const int quad = lane >> 4;           // k-octet within chunk
    const int b_m  = mt*16 + nn;          // this lane's A batch row
    const int SA   = (LAYER==0)?FF:HH;    // WA row stride
    constexpr int NC = (LAYER==0)?12:16;  // K chunks per K-half

    // ---- one-time: W-hi B-fragments into registers; W-lo fragments into LDS ----
    short8 wHi[2][NC];
    {
#pragma unroll
        for (int nt=0; nt<2; ++nt){
            const int jg = ((nn>>2)<<9) + (tile<<3) + (nt<<2) + (nn&3); // gate row for col nn of tile nt
            const float* rA = WA + (size_t)jg*SA;
            const float* rB = WB + (size_t)jg*HH;
#pragma unroll
            for (int c=0;c<NC;++c){
                const float* p;
                if (LAYER==1)    p = (kh ? rB : rA) + c*32 + quad*8;        // kh=0: Wih1(h0), kh=1: Whh1(h1)
                else if (kh==1)  p = rB + (c+4)*32 + quad*8;                // h0 k 128..511
                else             p = (c<8) ? (rA + c*32 + quad*8)           // 8 x-chunks
                                           : (rB + (c-8)*32 + quad*8);      // + 4 h0-chunks (k 0..127)
                float v[8];
#pragma unroll
                for (int j=0;j<8;++j) v[j]=p[j];
                short8 lo;
                split8(v, wHi[nt][c], lo);
                if (mt==0) sm->wlo[((kh*16 + c)*2 + nt)*64 + quad*16 + nn] = lo;
            }
        }
    }

    // ---- epilogue thread state: bias regs + register-resident c ----
    const int b_e = tid>>3, ul = tid&7;   // thread -> (batch, unit-in-block)
    float br[4]; float creg = 0.f;
#pragma unroll
    for (int g=0; g<4; ++g){
        const int jgb = (g<<9) + (tile<<3) + ul;
        br[g] = bi[jgb] + bh[jgb];
    }

    // h chunk: A-frag load shared across both N-tiles; 6 MFMAs (3 per tile)
#define CHUNK_H(SRCP, CIDX) { \
        const unsigned* p_ = (SRCP); \
        HU u; u.q[0]=ld8coh(p_); u.q[1]=ld8coh(p_+2); u.q[2]=ld8coh(p_+4); u.q[3]=ld8coh(p_+6); \
        const short8 aH = __builtin_shufflevector(u.v,u.v,0,2,4,6,8,10,12,14); \
        const short8 aL = __builtin_shufflevector(u.v,u.v,1,3,5,7,9,11,13,15); \
        const short8 l0 = sm->wlo[((kh*16+(CIDX))*2+0)*64 + quad*16 + nn]; \
        const short8 l1 = sm->wlo[((kh*16+(CIDX))*2+1)*64 + quad*16 + nn]; \
        aH0 = MFMA(aH, wHi[0][CIDX], aH0); \
        aM0 = MFMA(aH, l0,           aM0); \
        aM0 = MFMA(aL, wHi[0][CIDX], aM0); \
        aH1 = MFMA(aH, wHi[1][CIDX], aH1); \
        aM1 = MFMA(aH, l1,           aM1); \
        aM1 = MFMA(aL, wHi[1][CIDX], aM1); }

    const int myblk = blockIdx.x;
    for (int s=0; s<=TT; ++s){
        // ---- dependency wait: layer0 slots >= s (both runs); layer1 slots >= s (L1) / s-2 (L0 WAR)
        if (wv==0){
            const int tgt = (lane<32) ? s : ((LAYER==0) ? (s-2) : s);
            const int* sp = slots + 2*lane;          // lanes 0..31: layer0 slots, 32..63: layer1
            for(;;){
                const unsigned long long q = ld8coh((const unsigned*)sp);
                const int v0 = (int)(unsigned)(q);
                const int v1 = (int)(unsigned)(q>>32);
                if (__all((v0>=tgt)&(v1>=tgt))) break;
                __builtin_amdgcn_s_sleep(1);
            }
        }
        __syncthreads();

        const bool active = LAYER ? (s>0) : (s<TT);
        if (active){
            const int t = LAYER ? (s-1) : s;
            f32x4 aH0={0.f,0.f,0.f,0.f}, aM0={0.f,0.f,0.f,0.f};
            f32x4 aH1={0.f,0.f,0.f,0.f}, aM1={0.f,0.f,0.f,0.f};

            if (LAYER==1){
                // kh=0: h0[s-1] (ring slot (s-1)&3); kh=1: h1[s-2] (slot s&1)
                const unsigned* src = kh ? (hp1 + (s&1)*32768)
                                         : (hp0 + ((s-1)&3)*32768);
#pragma unroll
                for (int c=0;c<16;++c)
                    CHUNK_H(src + ((c*4+quad)*64 + b_m)*8, c);
            } else {
                const unsigned* src = hp0 + ((s+3)&3)*32768;   // h0[s-1]
                if (kh==0){
                    const float* xp = x + ((size_t)b_m*TT + t)*FF + quad*8;
#pragma unroll
                    for (int c=0;c<8;++c){
                        float v[8];
                        const float4 a0 = *(const float4*)(xp + c*32);
                        const float4 a1 = *(const float4*)(xp + c*32 + 4);
                        v[0]=a0.x; v[1]=a0.y; v[2]=a0.z; v[3]=a0.w;
                        v[4]=a1.x; v[5]=a1.y; v[6]=a1.z; v[7]=a1.w;
                        short8 aH, aL; split8(v, aH, aL);
                        const short8 l0 = sm->wlo[((kh*16+c)*2+0)*64 + quad*16 + nn];
                        const short8 l1 = sm->wlo[((kh*16+c)*2+1)*64 + quad*16 + nn];
                        aH0 = MFMA(aH, wHi[0][c], aH0);
                        aM0 = MFMA(aH, l0,        aM0);
                        aM0 = MFMA(aL, wHi[0][c], aM0);
                        aH1 = MFMA(aH, wHi[1][c], aH1);
                        aM1 = MFMA(aH, l1,        aM1);
                        aM1 = MFMA(aL, wHi[1][c], aM1);
                    }
#pragma unroll
                    for (int c2=0;c2<4;++c2)
                        CHUNK_H(src + ((c2*4+quad)*64 + b_m)*8, 8+c2);
                } else {
#pragma unroll
                    for (int c=0;c<12;++c)
                        CHUNK_H(src + (((c+4)*4+quad)*64 + b_m)*8, c);
                }
            }

            // ---- combine K-halves via LDS, then fused gate epilogue ----
#pragma unroll
            for (int r=0;r<4;++r){
                sm->part[kh][mt][quad*4+r][nn]    = aH0[r]+aM0[r];
                sm->part[kh][mt][quad*4+r][16+nn] = aH1[r]+aM1[r];
            }
            __syncthreads();
            {
                const int mte = b_e>>4, mr = b_e&15;
                const int ntl = ul>>2,  uq = ul&3;
                float pre[4];
#pragma unroll
                for (int g=0; g<4; ++g){
                    const int col = ntl*16 + (g<<2) + uq;
                    pre[g] = sm->part[0][mte][mr][col] + sm->part[1][mte][mr][col] + br[g];
                }
                const float iv = sigmoidf_(pre[0]);
                const float fv = sigmoidf_(pre[1]);
                const float gv = tanhf(pre[2]);
                const float ov = sigmoidf_(pre[3]);
                creg = fv*creg + iv*gv;                      // c in a register
                const float hn = ov * tanhf(creg);
                const unsigned short hh = f2bf(hn);
                const unsigned short hl = f2bf(hn - bf2f(hh));
                const unsigned pk = ((unsigned)hl<<16) | (unsigned)hh;
                const int idx = (tile*64 + b_e)*8 + ul;      // hA[koct=tile][b][8] pairs, coalesced
                if (LAYER==0) st4coh(hp0 + (s&3)*32768 + idx, pk);
                else {
                    st4coh(hp1 + ((s-1)&1)*32768 + idx, pk);
                    out[((size_t)b_e*TT + t)*HH + (tile*8 + ul)] = hn;  // fp32, plain cached
                }
            }
        }

        // ---- publish progress: vmcnt(0) drain in syncthreads acks coherent
        // h stores before the token store issues ----
        __syncthreads();
        if (tid==0) stslot(slots + myblk, s+1);
    }
#undef CHUNK_H
}

__global__ void __launch_bounds__(512,2) lstm_persist(
    const float* __restrict__ x,
    const float* __restrict__ Wih0, const float* __restrict__ Whh0,
    const float* __restrict__ bi0,  const float* __restrict__ bh0,
    const float* __restrict__ Wih1, const float* __restrict__ Whh1,
    const float* __restrict__ bi1,  const float* __restrict__ bh1,
    unsigned* hp0, unsigned* hp1, float* out, int* slots)
{
    __shared__ SMem sm;
    const int layer = blockIdx.x>>6, tile = blockIdx.x&63;
    if (layer==0) run<0>(x, Wih0, Whh0, bi0, bh0, hp0, hp1, out, slots, tile, &sm);
    else          run<1>(x, Wih1, Whh1, bi1, bh1, hp0, hp1, out, slots, tile, &sm);
}

extern "C" void kernel_launch(void* const* d_in, const int* in_sizes, int n_in,
                              void* d_out, int out_size, void* d_ws, size_t ws_size,
                              hipStream_t stream) {
    (void)in_sizes; (void)n_in; (void)out_size; (void)ws_size;
    const float* x    = (const float*)d_in[0];
    const float* Wih0 = (const float*)d_in[1];
    const float* Whh0 = (const float*)d_in[2];
    const float* bi0  = (const float*)d_in[3];
    const float* bh0  = (const float*)d_in[4];
    const float* Wih1 = (const float*)d_in[5];
    const float* Whh1 = (const float*)d_in[6];
    const float* bi1  = (const float*)d_in[7];
    const float* bh1  = (const float*)d_in[8];
    float* out = (float*)d_out;
    unsigned* ws = (unsigned*)d_ws;

    // ws (uints): hp0 ring[4][32768] | hp1 ring[2][32768] | slots[128]
    unsigned* hp0 = ws;                   // 4 slots x 128KB
    unsigned* hp1 = ws + 4*32768;         // 2 slots x 128KB
    int* slots    = (int*)(ws + 6*32768);

    hipMemsetAsync(d_ws, 0, (6*32768 + 128)*sizeof(unsigned), stream);

    void* args[] = {
        (void*)&x, (void*)&Wih0, (void*)&Whh0, (void*)&bi0, (void*)&bh0,
        (void*)&Wih1, (void*)&Whh1, (void*)&bi1, (void*)&bh1,
        (void*)&hp0, (void*)&hp1, (void*)&out, (void*)&slots
    };
    hipLaunchCooperativeKernel((const void*)lstm_persist, dim3(NB), dim3(512),
                               args, 0, stream);
}